// Round 13
// baseline (20.664 us; speedup 1.0000x reference)
//
#include <hip/hip_runtime.h>

// TransE 'rhs': pred[b,n] = MARGIN - ||(s+r)[b] - e[n]||_2. B=32,N=200k,D=64 fp32.
//
// R12 post-mortem: throughput tracks waves/CU (1.2/3.0/3.8 TB/s @ 3/6/10);
// LDS (16KB/wave) is the occupancy binder. R13: 16-row tiles (4KB) with
// mfma_f32_16x16x32_bf16 -> 8KB/wave -> 32KB per 4-wave block -> 16-20
// waves/CU. Same proven pieces: hi+lo q / hi-only e bf16 split, eswz
// fragment swizzle, counted vmcnt(4) dbuf rotation (never 0 mid-loop),
// preds in regs, oT overlay + 1KB-contiguous row stores.

#define MARGIN 9.0f

typedef __attribute__((ext_vector_type(8))) short bf16x8;
typedef __attribute__((ext_vector_type(4))) float f32x4;

typedef __attribute__((address_space(3))) void        lds_vp;
typedef __attribute__((address_space(1))) const void  glb_vp;

__device__ __forceinline__ unsigned eswz(unsigned p) {   // in-row involution
    return p ^ (((p >> 8) & 15u) << 4);
}

__global__ __launch_bounds__(256, 4)
void transe13(const float* __restrict__ s_emb,
              const float* __restrict__ rel_emb,
              const float* __restrict__ emb_e,
              float* __restrict__ out, int N)
{
    __shared__ __align__(16) char lds[32768];   // 4 waves x 2 x 4KB
    const int t = threadIdx.x, w = t >> 6, lane = t & 63;
    const int c16 = lane & 15;       // frag row/col within 16-tile
    const int g   = lane >> 4;       // k-group 0..3
    char* const B0 = lds + w * 8192;
    char* const B1 = B0 + 4096;
    const int  ntile = N >> 4;                   // 12500 tiles of 16 rows
    const long Tw = (long)blockIdx.x * 16 + w * 4;

    // ---- 1. s,r loads to regs (issued first), then first e-DMA ----
    const float4* s4 = (const float4*)s_emb;
    const float4* r4 = (const float4*)rel_emb;
    float4 sv[8], rv[8];
#pragma unroll
    for (int k = 0; k < 8; ++k) sv[k] = s4[k*64 + lane];
#pragma unroll
    for (int k = 0; k < 8; ++k) rv[k] = r4[k*64 + lane];

    auto dma4 = [&](long tile, char* l) {        // 4 x 1KB coalesced DMA
        const long ts = (tile < ntile) ? tile : (long)(ntile - 1);
        const char* gp = (const char*)emb_e + ts * 4096;
#pragma unroll
        for (int k = 0; k < 4; ++k) {
            const unsigned p = (unsigned)(k*1024 + lane*16);
            __builtin_amdgcn_global_load_lds((glb_vp*)(gp + eswz(p)),
                                             (lds_vp*)(l + k*1024), 16, 0, 0);
        }
    };
    dma4(Tw + 0, B1);          // T0 flies during the whole q prologue

    // ---- 2. q prologue: two 16-row passes through B0 ----
    const unsigned fbase = (unsigned)(c16*256 + g*32);   // + ks*128
    bf16x8 qh[2][2], ql[2][2];
    float qnp[2];
#pragma unroll
    for (int mh = 0; mh < 2; ++mh) {
#pragma unroll
        for (int k = 0; k < 4; ++k) {            // q rows mh*16 .. mh*16+15
            const int kk = mh*4 + k;
            const unsigned p = (unsigned)(k*1024 + lane*16);
            float4 q = make_float4(sv[kk].x+rv[kk].x, sv[kk].y+rv[kk].y,
                                   sv[kk].z+rv[kk].z, sv[kk].w+rv[kk].w);
            *(float4*)(B0 + eswz(p)) = q;
        }
        asm volatile("s_waitcnt lgkmcnt(0)" ::: "memory");
        float qq = 0.f;
#pragma unroll
        for (int ks = 0; ks < 2; ++ks) {
            const unsigned pe = eswz(fbase + ks*128);
            float4 q0 = *(const float4*)(B0 + pe);
            float4 q1 = *(const float4*)(B0 + (pe ^ 16));
            const float qf[8] = {q0.x,q0.y,q0.z,q0.w, q1.x,q1.y,q1.z,q1.w};
#pragma unroll
            for (int i = 0; i < 8; ++i) {
                const float f = qf[i];
                qq = fmaf(f, f, qq);
                const unsigned u = __float_as_uint(f);
                qh[mh][ks][i] = (short)(u >> 16);                      // hi
                const float lo = f - __uint_as_float(u & 0xFFFF0000u); // exact
                ql[mh][ks][i] = (short)(__float_as_uint(lo) >> 16);
            }
        }
        qnp[mh] = qq;
        asm volatile("s_waitcnt lgkmcnt(0)" ::: "memory");  // reads retired
    }
    dma4(Tw + 1, B0);                            // FIFO: T0(4), T1(4)

    // qn for acc rows: acc row b = mh*16 + g*4 + j; ||q_b||^2 lives at lane b&15
    float qn0 = qnp[0]; qn0 += __shfl_xor(qn0, 16); qn0 += __shfl_xor(qn0, 32);
    float qn1 = qnp[1]; qn1 += __shfl_xor(qn1, 16); qn1 += __shfl_xor(qn1, 32);
    float qn_need[8];
#pragma unroll
    for (int j = 0; j < 4; ++j) {
        qn_need[j]     = __shfl(qn0, g*4 + j);
        qn_need[4 + j] = __shfl(qn1, g*4 + j);
    }

    // ---- 3. per-tile compute: 4 ds_read_b128, 8 MFMA 16x16x32, finish ----
    auto tile_full = [&](const char* L, f32x4& o0, f32x4& o1) {
        f32x4 a0 = {0.f,0.f,0.f,0.f}, a1 = {0.f,0.f,0.f,0.f};
        float ep = 0.f;
#pragma unroll
        for (int ks = 0; ks < 2; ++ks) {
            const unsigned pe = eswz(fbase + ks*128);
            float4 e0 = *(const float4*)(L + pe);
            float4 e1 = *(const float4*)(L + (pe ^ 16));
            ep = fmaf(e0.x, e0.x, ep); ep = fmaf(e0.y, e0.y, ep);
            ep = fmaf(e0.z, e0.z, ep); ep = fmaf(e0.w, e0.w, ep);
            ep = fmaf(e1.x, e1.x, ep); ep = fmaf(e1.y, e1.y, ep);
            ep = fmaf(e1.z, e1.z, ep); ep = fmaf(e1.w, e1.w, ep);
            unsigned ew[4];
            ew[0] = __builtin_amdgcn_perm(__float_as_uint(e0.y),
                                          __float_as_uint(e0.x), 0x07060302u);
            ew[1] = __builtin_amdgcn_perm(__float_as_uint(e0.w),
                                          __float_as_uint(e0.z), 0x07060302u);
            ew[2] = __builtin_amdgcn_perm(__float_as_uint(e1.y),
                                          __float_as_uint(e1.x), 0x07060302u);
            ew[3] = __builtin_amdgcn_perm(__float_as_uint(e1.w),
                                          __float_as_uint(e1.z), 0x07060302u);
            bf16x8 eh;
            __builtin_memcpy(&eh, ew, 16);
            a0 = __builtin_amdgcn_mfma_f32_16x16x32_bf16(qh[0][ks], eh, a0, 0,0,0);
            a0 = __builtin_amdgcn_mfma_f32_16x16x32_bf16(ql[0][ks], eh, a0, 0,0,0);
            a1 = __builtin_amdgcn_mfma_f32_16x16x32_bf16(qh[1][ks], eh, a1, 0,0,0);
            a1 = __builtin_amdgcn_mfma_f32_16x16x32_bf16(ql[1][ks], eh, a1, 0,0,0);
        }
        float en = ep; en += __shfl_xor(en, 16); en += __shfl_xor(en, 32);
#pragma unroll
        for (int j = 0; j < 4; ++j) {
            const float d0 = fmaxf(fmaf(-2.f, a0[j], qn_need[j]     + en), 0.f);
            const float d1 = fmaxf(fmaf(-2.f, a1[j], qn_need[4 + j] + en), 0.f);
            o0[j] = MARGIN - sqrtf(d0);
            o1[j] = MARGIN - sqrtf(d1);
        }
    };

    f32x4 p00, p01, p10, p11, p20, p21, p30, p31;
    asm volatile("s_waitcnt vmcnt(4)" ::: "memory");    // T0 done, T1 flying
    tile_full(B1, p00, p01);
    asm volatile("s_waitcnt lgkmcnt(0)" ::: "memory");  // B1 reads retired
    dma4(Tw + 2, B1);                                   // FIFO: T1, T2
    asm volatile("s_waitcnt vmcnt(4)" ::: "memory");    // T1 done
    tile_full(B0, p10, p11);
    asm volatile("s_waitcnt lgkmcnt(0)" ::: "memory");
    dma4(Tw + 3, B0);                                   // FIFO: T2, T3
    asm volatile("s_waitcnt vmcnt(4)" ::: "memory");    // T2 done
    tile_full(B1, p20, p21);
    asm volatile("s_waitcnt vmcnt(0)" ::: "memory");    // T3 done
    tile_full(B0, p30, p31);

    // ---- 4. preds -> oT [32 b][256 n] overlay, clean 1KB-row stores ----
    __syncthreads();                      // all waves done with e-buffers
    float* oT = (float*)lds;
    const int nl = w*64 + c16;
#pragma unroll
    for (int j = 0; j < 4; ++j) {
        const int b0r = g*4 + j, b1r = 16 + g*4 + j;
        oT[b0r*256 + nl +  0] = p00[j];
        oT[b1r*256 + nl +  0] = p01[j];
        oT[b0r*256 + nl + 16] = p10[j];
        oT[b1r*256 + nl + 16] = p11[j];
        oT[b0r*256 + nl + 32] = p20[j];
        oT[b1r*256 + nl + 32] = p21[j];
        oT[b0r*256 + nl + 48] = p30[j];
        oT[b1r*256 + nl + 48] = p31[j];
    }
    __syncthreads();

    const long nb = (long)blockIdx.x * 256;
#pragma unroll
    for (int k = 0; k < 8; ++k) {         // wave w: rows w*8..w*8+7, 1KB each
        const int  rb  = w*8 + k;
        const long col = nb + lane*4;
        if (col + 3 < N) {
            const float4 v = *(const float4*)(oT + rb*256 + lane*4);
            *(float4*)(out + (size_t)rb * N + col) = v;
        }
    }
}

extern "C" void kernel_launch(void* const* d_in, const int* in_sizes, int n_in,
                              void* d_out, int out_size, void* d_ws, size_t ws_size,
                              hipStream_t stream) {
    const float* s = (const float*)d_in[0];
    const float* r = (const float*)d_in[1];
    const float* e = (const float*)d_in[2];
    float* out = (float*)d_out;

    const int N = in_sizes[2] / 64;            // 200000
    const int grid = (N + 255) / 256;          // 782 blocks x 256 threads

    transe13<<<grid, 256, 0, stream>>>(s, r, e, out, N);
}